// Round 12
// baseline (172.219 us; speedup 1.0000x reference)
//
#include <hip/hip_runtime.h>

// Trilinear interpolation of a 128^3 x 16 latent grid at 2M random points.
// 3-phase spatial counting sort, WAVE-PRIVATE phase B (zero barriers):
//   A1: counting-sort points into 512 super-bins (8x8x8), segments in d_out
//       (fully overwritten by B afterwards).
//   A2: per super-bin, counting-sort its segment into 128 children -> 65536
//       fine bins (32x32x64; 4x4x2 grid cells each) in d_ws.
//   B : one bin per WAVE. Each wave DMA-stages its bin's 5x5x3-row latent
//       tile (4.8 KB) into its private LDS slice via global_load_lds
//       (source-swizzled for bank spread), prefetches all tuples, waits once
//       on its own vmcnt, computes. 20 KB LDS/block -> 8 blocks/CU = 32
//       waves/CU; no __syncthreads anywhere.
// Spill list + cleanup kernel guard the capacity overflow paths.

constexpr int   GRID_RES   = 128;
constexpr int   LATENT_DIM = 16;
constexpr float SCALE      = 126.0f;          // GRID_RES - 2

constexpr int NSUPER    = 512;                 // 8x8x8
constexpr int NCHILD    = 128;                 // 4x4x8 per super
constexpr int NFINE     = NSUPER * NCHILD;     // 65536 (32x32x64)
constexpr int CAP_F     = 56;                  // mean 32, sigma ~5.7 (4.2 sigma)
constexpr int SPILL_CAP = 16384;
constexpr int NROWS     = 5 * 5 * 3;           // 75 staged latent rows
constexpr int NXCD      = 8;

// d_ws layout
constexpr size_t SCUR_OFF     = 0;             // 512 u32
constexpr size_t FCUR_OFF     = 2048;          // 65536 u32
constexpr size_t SPILLCUR_OFF = 264192;        // 1 u32
constexpr size_t CUR_BYTES    = 265216;        // memset region
constexpr size_t FINE_OFF     = CUR_BYTES;
constexpr size_t FINE_BYTES   = (size_t)NFINE * CAP_F * 16;   // 58.7 MB
constexpr size_t SPILL_OFF    = FINE_OFF + FINE_BYTES;
constexpr size_t WS_NEEDED    = SPILL_OFF + (size_t)SPILL_CAP * 16;

typedef float fvec4 __attribute__((ext_vector_type(4)));
typedef const __attribute__((address_space(1))) unsigned int* gptr_t;
typedef __attribute__((address_space(3))) unsigned int*       lptr_t;

// ---- helpers ----------------------------------------------------------------

__device__ __forceinline__ void fine_bin(float x, float y, float z,
                                         int* s, int* c) {
    const int lx = min(max((int)floorf(x * SCALE), 0), 125);
    const int ly = min(max((int)floorf(y * SCALE), 0), 125);
    const int lz = min(max((int)floorf(z * SCALE), 0), 125);
    const int fbx = lx >> 2;   // [0,32)
    const int fby = ly >> 2;   // [0,32)
    const int fbz = lz >> 1;   // [0,63]
    *s = ((fbx >> 2) << 6) | ((fby >> 2) << 3) | (fbz >> 3);   // [0,512)
    *c = ((fbx & 3) << 5) | ((fby & 3) << 3) | (fbz & 7);      // [0,128)
}

__device__ __forceinline__ void corner_setup(
    float sx, float sy, float sz,
    int cx[2], int cy[2], int cz[2],
    float fx[2], float fy[2], float fz[2])
{
    const float bx = floorf(sx), by = floorf(sy), bz = floorf(sz);
    const int ix = (int)bx, iy = (int)by, iz = (int)bz;
    const float wbx = sx - bx, wby = sy - by, wbz = sz - bz;
    cx[0] = min(max(ix,     0), GRID_RES - 1);
    cx[1] = min(max(ix + 1, 0), GRID_RES - 1);
    cy[0] = min(max(iy,     0), GRID_RES - 1);
    cy[1] = min(max(iy + 1, 0), GRID_RES - 1);
    cz[0] = min(max(iz,     0), GRID_RES - 1);
    cz[1] = min(max(iz + 1, 0), GRID_RES - 1);
    fx[0] = 1.0f - wbx; fx[1] = wbx;
    fy[0] = 1.0f - wby; fy[1] = wby;
    fz[0] = 1.0f - wbz; fz[1] = wbz;
}

__device__ __forceinline__ fvec4 trilerp_q(
    const float* __restrict__ latents,
    const int cx[2], const int cy[2], const int cz[2],
    const float fx[2], const float fy[2], const float fz[2], int q)
{
    fvec4 acc = (fvec4)(0.0f);
    #pragma unroll
    for (int ox = 0; ox < 2; ++ox)
      #pragma unroll
      for (int oy = 0; oy < 2; ++oy)
        #pragma unroll
        for (int oz = 0; oz < 2; ++oz) {
            const int flat = cx[ox] * (GRID_RES * GRID_RES) + cy[oy] * GRID_RES + cz[oz];
            const float w = fx[ox] * fy[oy] * fz[oz];
            const fvec4 f = *reinterpret_cast<const fvec4*>(
                latents + (size_t)flat * LATENT_DIM + q * 4);
            acc += w * f;
        }
    return acc;
}

// ---- A1: counting-sort into 512 super-bins (segments in d_out) --------------

__global__ __launch_bounds__(256) void binA1(
    const float* __restrict__ pts, int n_pts,
    unsigned* __restrict__ scur, fvec4* __restrict__ superSeg, int cap_s,
    unsigned* __restrict__ spillcur, fvec4* __restrict__ spillSeg)
{
    __shared__ unsigned cnt[NSUPER], base[NSUPER], off[NSUPER];
    const int t = threadIdx.x;
    for (int i = t; i < NSUPER; i += 256) { cnt[i] = 0; off[i] = 0; }
    __syncthreads();

    const int chunk = (n_pts + gridDim.x - 1) / gridDim.x;
    const int lo = blockIdx.x * chunk;
    const int hi = min(lo + chunk, n_pts);

    for (int p = lo + t; p < hi; p += 256) {
        int s, c;
        fine_bin(pts[3*p], pts[3*p+1], pts[3*p+2], &s, &c);
        atomicAdd(&cnt[s], 1u);
    }
    __syncthreads();
    for (int i = t; i < NSUPER; i += 256) base[i] = atomicAdd(&scur[i], cnt[i]);
    __syncthreads();
    for (int p = lo + t; p < hi; p += 256) {
        const float x = pts[3*p], y = pts[3*p+1], z = pts[3*p+2];
        int s, c;
        fine_bin(x, y, z, &s, &c);
        const unsigned slot = base[s] + atomicAdd(&off[s], 1u);
        fvec4 tp; tp.x = x; tp.y = y; tp.z = z; tp.w = __uint_as_float((unsigned)p);
        if (slot < (unsigned)cap_s) {
            superSeg[(size_t)s * cap_s + slot] = tp;
        } else {                                   // ~impossible; keep correct
            const unsigned sp = atomicAdd(spillcur, 1u);
            if (sp < (unsigned)SPILL_CAP) spillSeg[sp] = tp;
        }
    }
}

// ---- A2: refine each super-bin into its 128 children ------------------------

__global__ __launch_bounds__(256) void binA2(
    const fvec4* __restrict__ superSeg, int cap_s,
    const unsigned* __restrict__ scur,
    unsigned* __restrict__ fcur, fvec4* __restrict__ fineSeg,
    unsigned* __restrict__ spillcur, fvec4* __restrict__ spillSeg)
{
    constexpr int SLICES = 2;
    const int super = blockIdx.x / SLICES;
    const int slice = blockIdx.x % SLICES;
    const unsigned n = min(scur[super], (unsigned)cap_s);
    const unsigned lo = (unsigned)(((unsigned long long)n * slice) / SLICES);
    const unsigned hi = (unsigned)(((unsigned long long)n * (slice + 1)) / SLICES);

    __shared__ unsigned cnt[NCHILD], base[NCHILD], off[NCHILD];
    const int t = threadIdx.x;
    if (t < NCHILD) { cnt[t] = 0; off[t] = 0; }
    __syncthreads();

    for (unsigned i = lo + t; i < hi; i += 256) {
        const fvec4 tp = superSeg[(size_t)super * cap_s + i];
        int s, c;
        fine_bin(tp.x, tp.y, tp.z, &s, &c);
        atomicAdd(&cnt[c], 1u);
    }
    __syncthreads();
    if (t < NCHILD) base[t] = atomicAdd(&fcur[super * NCHILD + t], cnt[t]);
    __syncthreads();
    for (unsigned i = lo + t; i < hi; i += 256) {
        const fvec4 tp = superSeg[(size_t)super * cap_s + i];
        int s, c;
        fine_bin(tp.x, tp.y, tp.z, &s, &c);
        const unsigned slot = base[c] + atomicAdd(&off[c], 1u);
        if (slot < (unsigned)CAP_F) {
            fineSeg[(size_t)(super * NCHILD + c) * CAP_F + slot] = tp;
        } else {
            const unsigned sp = atomicAdd(spillcur, 1u);
            if (sp < (unsigned)SPILL_CAP) spillSeg[sp] = tp;
        }
    }
}

// ---- B: one bin per wave, wave-private LDS slice, no barriers ---------------
// Bin covers cells [bx*4,+4) x [by*4,+4) x [bz*2,+2); staged tile 5x5x3 = 75
// rows (64 B each) in a 5 KB wave-private LDS slice. DMA-linear layout with
// SOURCE swizzle: LDS unit u = r*4+j holds quarter (j+r)&3 of row r; reader
// finds quarter q of row r at unit r*4+((q-r)&3).

__global__ __launch_bounds__(256, 8) void binB(
    const fvec4* __restrict__ fineSeg, const unsigned* __restrict__ fcur,
    const float* __restrict__ latents, float* __restrict__ out)
{
    __shared__ __align__(16) float lat[4][1280];   // 5 KB per wave, 20 KB/block

    const int orig = blockIdx.x;                   // 16384 blocks
    const int blk  = (orig & (NXCD - 1)) * (gridDim.x / NXCD) + (orig >> 3);

    const int t    = threadIdx.x;
    const int wave = t >> 6, lane = t & 63;
    const int q    = lane & 3, g = lane >> 2;      // q: feature quarter, g: point slot

    const int fid = blk * 4 + wave;
    const int s   = fid >> 7, c = fid & 127;
    const int bx = ((s >> 6) << 2)       | (c >> 5);          // [0,32)
    const int by = (((s >> 3) & 7) << 2) | ((c >> 3) & 3);    // [0,32)
    const int bz = ((s & 7) << 3)        | (c & 7);           // [0,64)

    const int n = (int)min(fcur[fid], (unsigned)CAP_F);   // n <= 56
    if (n == 0) return;                                   // wave-uniform early out
    const fvec4* seg = fineSeg + (size_t)fid * CAP_F;
    float* lw = &lat[wave][0];

    // ---- wave-level DMA stage: 5 rounds x 64 lanes of 16 B ------------------
    #pragma unroll
    for (int k = 0; k < 5; ++k) {
        const int u  = k * 64 + lane;
        const int uc = min(u, NROWS * 4 - 1);          // clamp tail into pad
        const int r  = uc >> 2, j = uc & 3;
        const int qs = (j + r) & 3;                    // source-side swizzle
        const int dx = r / 15, rem = r - dx * 15, dy = rem / 3, dz = rem - dy * 3;
        const int gx = min(bx * 4 + dx, 127);
        const int gy = min(by * 4 + dy, 127);
        const int gz = min(bz * 2 + dz, 127);
        const float* src = latents
            + ((size_t)(((gx << 7) | gy) << 7 | gz)) * LATENT_DIM + qs * 4;
        float* dst = lw + k * 256;                     // wave-uniform base; HW adds lane*16B
        __builtin_amdgcn_global_load_lds((gptr_t)(const void*)src,
                                         (lptr_t)(void*)dst, 16, 0, 0);
    }

    // ---- prefetch all tuples (clamped addresses, always issued) -------------
    const int hi = n - 1;
    fvec4 tp[4];
    #pragma unroll
    for (int k = 0; k < 4; ++k)
        tp[k] = __builtin_nontemporal_load(&seg[min(k * 16 + g, hi)]);

    // ---- single wave-level wait; no barriers --------------------------------
    asm volatile("s_waitcnt vmcnt(0)" ::: "memory");
    __builtin_amdgcn_sched_barrier(0);

    // ---- compute ------------------------------------------------------------
    #pragma unroll
    for (int k = 0; k < 4; ++k) {
        if (k * 16 + g < n) {
            const fvec4 tpv = tp[k];
            const unsigned idx = __float_as_uint(tpv.w);
            const float sxv = tpv.x * SCALE, syv = tpv.y * SCALE, szv = tpv.z * SCALE;
            const float bxf = floorf(sxv), byf = floorf(syv), bzf = floorf(szv);
            const int lx = (int)bxf - bx * 4;           // [0,3]
            const int ly = (int)byf - by * 4;           // [0,3]
            const int lz = (int)bzf - bz * 2;           // [0,1]
            const float wbx = sxv - bxf, wby = syv - byf, wbz = szv - bzf;
            const float fx[2] = {1.0f - wbx, wbx};
            const float fy[2] = {1.0f - wby, wby};
            const float fz[2] = {1.0f - wbz, wbz};

            fvec4 acc = (fvec4)(0.0f);
            #pragma unroll
            for (int ox = 0; ox < 2; ++ox)
              #pragma unroll
              for (int oy = 0; oy < 2; ++oy)
                #pragma unroll
                for (int oz = 0; oz < 2; ++oz) {
                    const int rr = (lx + ox) * 15 + (ly + oy) * 3 + (lz + oz);
                    const int unit = rr * 4 + ((q - rr) & 3);
                    const fvec4 f = *reinterpret_cast<const fvec4*>(&lw[unit * 4]);
                    acc += (fx[ox] * fy[oy] * fz[oz]) * f;
                }

            __builtin_nontemporal_store(acc,
                reinterpret_cast<fvec4*>(out + (size_t)idx * LATENT_DIM + q * 4));
        }
    }
}

// ---- spill cleanup (normally tiny) ------------------------------------------

__global__ __launch_bounds__(256) void spillK(
    const fvec4* __restrict__ spillSeg, const unsigned* __restrict__ spillcur,
    const float* __restrict__ latents, float* __restrict__ out)
{
    const unsigned n = min(*spillcur, (unsigned)SPILL_CAP);
    for (unsigned i = blockIdx.x * 256 + threadIdx.x; i < n; i += gridDim.x * 256) {
        const fvec4 tp = spillSeg[i];
        const unsigned idx = __float_as_uint(tp.w);
        int cx[2], cy[2], cz[2]; float fx[2], fy[2], fz[2];
        corner_setup(tp.x * SCALE, tp.y * SCALE, tp.z * SCALE, cx, cy, cz, fx, fy, fz);
        #pragma unroll
        for (int q = 0; q < 4; ++q) {
            const fvec4 acc = trilerp_q(latents, cx, cy, cz, fx, fy, fz, q);
            *reinterpret_cast<fvec4*>(out + (size_t)idx * LATENT_DIM + q * 4) = acc;
        }
    }
}

// ---- fallback: direct version ----------------------------------------------

__global__ __launch_bounds__(256) void trilerp_direct(
    const float* __restrict__ pts, const float* __restrict__ latents,
    float* __restrict__ out, int n_pts)
{
    const int tid = blockIdx.x * blockDim.x + threadIdx.x;
    const int p = tid >> 2;
    const int q = tid & 3;
    if (p >= n_pts) return;
    int cx[2], cy[2], cz[2]; float fx[2], fy[2], fz[2];
    corner_setup(pts[3*p] * SCALE, pts[3*p+1] * SCALE, pts[3*p+2] * SCALE,
                 cx, cy, cz, fx, fy, fz);
    const fvec4 acc = trilerp_q(latents, cx, cy, cz, fx, fy, fz, q);
    *reinterpret_cast<fvec4*>(out + (size_t)p * LATENT_DIM + q * 4) = acc;
}

// ---- launch -----------------------------------------------------------------

extern "C" void kernel_launch(void* const* d_in, const int* in_sizes, int n_in,
                              void* d_out, int out_size, void* d_ws, size_t ws_size,
                              hipStream_t stream) {
    const float* pts     = (const float*)d_in[0];
    const float* latents = (const float*)d_in[1];
    float* out = (float*)d_out;
    const int n_pts = in_sizes[0] / 3;

    const int cap_s = (int)(((size_t)out_size * 4) / (NSUPER * 16));  // tuples/super seg

    if (ws_size < WS_NEEDED || cap_s * (size_t)NSUPER * 16 > (size_t)out_size * 4 ||
        (size_t)cap_s < (size_t)n_pts / 128) {
        const int total = n_pts * 4;
        trilerp_direct<<<(total + 255) / 256, 256, 0, stream>>>(pts, latents, out, n_pts);
        return;
    }

    unsigned* scur     = (unsigned*)((char*)d_ws + SCUR_OFF);
    unsigned* fcur     = (unsigned*)((char*)d_ws + FCUR_OFF);
    unsigned* spillcur = (unsigned*)((char*)d_ws + SPILLCUR_OFF);
    fvec4*    fineSeg  = (fvec4*)((char*)d_ws + FINE_OFF);
    fvec4*    spillSeg = (fvec4*)((char*)d_ws + SPILL_OFF);
    fvec4*    superSeg = (fvec4*)d_out;                 // reused as scratch

    hipMemsetAsync(d_ws, 0, CUR_BYTES, stream);
    binA1<<<256, 256, 0, stream>>>(pts, n_pts, scur, superSeg, cap_s,
                                   spillcur, spillSeg);
    binA2<<<NSUPER * 2, 256, 0, stream>>>(superSeg, cap_s, scur,
                                          fcur, fineSeg, spillcur, spillSeg);
    binB<<<NFINE / 4, 256, 0, stream>>>(fineSeg, fcur, latents, out);
    spillK<<<16, 256, 0, stream>>>(spillSeg, spillcur, latents, out);
}

// Round 13
// 138.021 us; speedup vs baseline: 1.2478x; 1.2478x over previous
//
#include <hip/hip_runtime.h>

// Trilinear interpolation of a 128^3 x 16 latent grid at 2M random points.
// 3-phase spatial counting sort, WAVE-PRIVATE phase B (zero barriers):
//   A1: counting-sort points into 512 super-bins (8x8x8), segments in d_out
//       (fully overwritten by B afterwards).
//   A2: per super-bin, counting-sort its segment into 64 children -> 32768
//       fine bins (32^3; 4x4x4 grid cells each) in d_ws. Tuples written
//       PRECOMPUTED: {wbx, wby, wbz, packed(idx | lx|ly|lz)} so phase B does
//       no floor/clamp/scale work.
//   B : one bin per WAVE, 2 lanes per point (32 pts/wave-pass). Wave DMA-
//       stages its 5x5x5-row latent tile (8 KB) into a private LDS slice
//       (XOR source swizzle), prefetches tuples, one vmcnt(0), computes.
//       No __syncthreads anywhere.
// Spill list + cleanup kernel guard the capacity overflow paths.

constexpr int   GRID_RES   = 128;
constexpr int   LATENT_DIM = 16;
constexpr float SCALE      = 126.0f;          // GRID_RES - 2

constexpr int NSUPER    = 512;                 // 8x8x8
constexpr int NCHILD    = 64;                  // 4x4x4 per super
constexpr int NFINE     = NSUPER * NCHILD;     // 32768 (32^3)
constexpr int CAP_F     = 96;                  // mean ~64, sigma ~8
constexpr int SPILL_CAP = 16384;
constexpr int NROWS     = 125;                 // 5x5x5 staged latent rows
constexpr int NXCD      = 8;

// d_ws layout
constexpr size_t SCUR_OFF     = 0;             // 512 u32
constexpr size_t FCUR_OFF     = 2048;          // 32768 u32
constexpr size_t SPILLCUR_OFF = 133120;        // 1 u32
constexpr size_t CUR_BYTES    = 134144;        // memset region
constexpr size_t FINE_OFF     = CUR_BYTES;
constexpr size_t FINE_BYTES   = (size_t)NFINE * CAP_F * 16;   // 48 MB
constexpr size_t SPILL_OFF    = FINE_OFF + FINE_BYTES;
constexpr size_t WS_NEEDED    = SPILL_OFF + (size_t)SPILL_CAP * 16;

typedef float fvec4 __attribute__((ext_vector_type(4)));
typedef const __attribute__((address_space(1))) unsigned int* gptr_t;
typedef __attribute__((address_space(3))) unsigned int*       lptr_t;

// ---- helpers ----------------------------------------------------------------

__device__ __forceinline__ void fine_bin(float x, float y, float z,
                                         int* s, int* c) {
    const int lx = min(max((int)floorf(x * SCALE), 0), 125);
    const int ly = min(max((int)floorf(y * SCALE), 0), 125);
    const int lz = min(max((int)floorf(z * SCALE), 0), 125);
    const int fbx = lx >> 2;   // [0,32)
    const int fby = ly >> 2;   // [0,32)
    const int fbz = lz >> 2;   // [0,32)
    *s = ((fbx >> 2) << 6) | ((fby >> 2) << 3) | (fbz >> 2);   // [0,512)
    *c = ((fbx & 3) << 4) | ((fby & 3) << 2) | (fbz & 3);      // [0,64)
}

__device__ __forceinline__ void corner_setup(
    float sx, float sy, float sz,
    int cx[2], int cy[2], int cz[2],
    float fx[2], float fy[2], float fz[2])
{
    const float bx = floorf(sx), by = floorf(sy), bz = floorf(sz);
    const int ix = (int)bx, iy = (int)by, iz = (int)bz;
    const float wbx = sx - bx, wby = sy - by, wbz = sz - bz;
    cx[0] = min(max(ix,     0), GRID_RES - 1);
    cx[1] = min(max(ix + 1, 0), GRID_RES - 1);
    cy[0] = min(max(iy,     0), GRID_RES - 1);
    cy[1] = min(max(iy + 1, 0), GRID_RES - 1);
    cz[0] = min(max(iz,     0), GRID_RES - 1);
    cz[1] = min(max(iz + 1, 0), GRID_RES - 1);
    fx[0] = 1.0f - wbx; fx[1] = wbx;
    fy[0] = 1.0f - wby; fy[1] = wby;
    fz[0] = 1.0f - wbz; fz[1] = wbz;
}

__device__ __forceinline__ fvec4 trilerp_q(
    const float* __restrict__ latents,
    const int cx[2], const int cy[2], const int cz[2],
    const float fx[2], const float fy[2], const float fz[2], int q)
{
    fvec4 acc = (fvec4)(0.0f);
    #pragma unroll
    for (int ox = 0; ox < 2; ++ox)
      #pragma unroll
      for (int oy = 0; oy < 2; ++oy)
        #pragma unroll
        for (int oz = 0; oz < 2; ++oz) {
            const int flat = cx[ox] * (GRID_RES * GRID_RES) + cy[oy] * GRID_RES + cz[oz];
            const float w = fx[ox] * fy[oy] * fz[oz];
            const fvec4 f = *reinterpret_cast<const fvec4*>(
                latents + (size_t)flat * LATENT_DIM + q * 4);
            acc += w * f;
        }
    return acc;
}

// ---- A1: counting-sort into 512 super-bins (segments in d_out) --------------

__global__ __launch_bounds__(256) void binA1(
    const float* __restrict__ pts, int n_pts,
    unsigned* __restrict__ scur, fvec4* __restrict__ superSeg, int cap_s,
    unsigned* __restrict__ spillcur, fvec4* __restrict__ spillSeg)
{
    __shared__ unsigned cnt[NSUPER], base[NSUPER], off[NSUPER];
    const int t = threadIdx.x;
    for (int i = t; i < NSUPER; i += 256) { cnt[i] = 0; off[i] = 0; }
    __syncthreads();

    const int chunk = (n_pts + gridDim.x - 1) / gridDim.x;
    const int lo = blockIdx.x * chunk;
    const int hi = min(lo + chunk, n_pts);

    for (int p = lo + t; p < hi; p += 256) {
        int s, c;
        fine_bin(pts[3*p], pts[3*p+1], pts[3*p+2], &s, &c);
        atomicAdd(&cnt[s], 1u);
    }
    __syncthreads();
    for (int i = t; i < NSUPER; i += 256) base[i] = atomicAdd(&scur[i], cnt[i]);
    __syncthreads();
    for (int p = lo + t; p < hi; p += 256) {
        const float x = pts[3*p], y = pts[3*p+1], z = pts[3*p+2];
        int s, c;
        fine_bin(x, y, z, &s, &c);
        const unsigned slot = base[s] + atomicAdd(&off[s], 1u);
        fvec4 tp; tp.x = x; tp.y = y; tp.z = z; tp.w = __uint_as_float((unsigned)p);
        if (slot < (unsigned)cap_s) {
            superSeg[(size_t)s * cap_s + slot] = tp;
        } else {                                   // ~impossible; keep correct
            const unsigned sp = atomicAdd(spillcur, 1u);
            if (sp < (unsigned)SPILL_CAP) spillSeg[sp] = tp;
        }
    }
}

// ---- A2: refine into 64 children; write PRECOMPUTED tuples ------------------
// fineSeg tuple = {wbx, wby, wbz, bits(idx | (lx&3)<<21 | (ly&3)<<23 | (lz&3)<<25)}

__global__ __launch_bounds__(256) void binA2(
    const fvec4* __restrict__ superSeg, int cap_s,
    const unsigned* __restrict__ scur,
    unsigned* __restrict__ fcur, fvec4* __restrict__ fineSeg,
    unsigned* __restrict__ spillcur, fvec4* __restrict__ spillSeg)
{
    constexpr int SLICES = 2;
    const int super = blockIdx.x / SLICES;
    const int slice = blockIdx.x % SLICES;
    const unsigned n = min(scur[super], (unsigned)cap_s);
    const unsigned lo = (unsigned)(((unsigned long long)n * slice) / SLICES);
    const unsigned hi = (unsigned)(((unsigned long long)n * (slice + 1)) / SLICES);

    __shared__ unsigned cnt[NCHILD], base[NCHILD], off[NCHILD];
    const int t = threadIdx.x;
    if (t < NCHILD) { cnt[t] = 0; off[t] = 0; }
    __syncthreads();

    for (unsigned i = lo + t; i < hi; i += 256) {
        const fvec4 tp = superSeg[(size_t)super * cap_s + i];
        int s, c;
        fine_bin(tp.x, tp.y, tp.z, &s, &c);
        atomicAdd(&cnt[c], 1u);
    }
    __syncthreads();
    if (t < NCHILD) base[t] = atomicAdd(&fcur[super * NCHILD + t], cnt[t]);
    __syncthreads();
    for (unsigned i = lo + t; i < hi; i += 256) {
        const fvec4 tp = superSeg[(size_t)super * cap_s + i];
        int s, c;
        fine_bin(tp.x, tp.y, tp.z, &s, &c);
        const unsigned slot = base[c] + atomicAdd(&off[c], 1u);
        if (slot < (unsigned)CAP_F) {
            // precompute fractional weights + local cell coords (bins are
            // 4-aligned in cell space -> local coord = cell & 3)
            const float sx = tp.x * SCALE, sy = tp.y * SCALE, sz = tp.z * SCALE;
            const float bxf = floorf(sx), byf = floorf(sy), bzf = floorf(sz);
            const int lx = min(max((int)bxf, 0), 125);
            const int ly = min(max((int)byf, 0), 125);
            const int lz = min(max((int)bzf, 0), 125);
            const unsigned bits = (__float_as_uint(tp.w) & 0x1FFFFFu)
                                | ((unsigned)(lx & 3) << 21)
                                | ((unsigned)(ly & 3) << 23)
                                | ((unsigned)(lz & 3) << 25);
            fvec4 pt;
            pt.x = sx - bxf; pt.y = sy - byf; pt.z = sz - bzf;
            pt.w = __uint_as_float(bits);
            fineSeg[(size_t)(super * NCHILD + c) * CAP_F + slot] = pt;
        } else {
            const unsigned sp = atomicAdd(spillcur, 1u);
            if (sp < (unsigned)SPILL_CAP) spillSeg[sp] = tp;   // raw tuple
        }
    }
}

// ---- B: one bin per wave, 2 lanes per point, wave-private LDS slice ---------
// Tile 5x5x5 = 125 rows (64 B) in 8 KB slice. Layout: 16-B unit
// u = rr*4 + (q ^ (rr&3));  source stage writes quarter (j ^ (r&3)) at unit
// (r,j) -> involution. Lane handles quarters q0=2*(lane&1), q0+1: second
// address is addr0 ^ 16.

__global__ __launch_bounds__(256, 5) void binB(
    const fvec4* __restrict__ fineSeg, const unsigned* __restrict__ fcur,
    const float* __restrict__ latents, float* __restrict__ out)
{
    __shared__ __align__(16) float lat[4][2048];   // 8 KB per wave

    const int orig = blockIdx.x;                   // 8192 blocks
    const int blk  = (orig & (NXCD - 1)) * (gridDim.x / NXCD) + (orig >> 3);

    const int t    = threadIdx.x;
    const int wave = t >> 6, lane = t & 63;
    const int q0   = (lane & 1) * 2;               // quarters q0, q0+1
    const int g    = lane >> 1;                    // point slot 0..31

    const int fid = blk * 4 + wave;
    const int s   = fid >> 6, c = fid & 63;
    const int bx = ((s >> 6) << 2)       | (c >> 4);          // [0,32)
    const int by = (((s >> 3) & 7) << 2) | ((c >> 2) & 3);    // [0,32)
    const int bz = ((s & 7) << 2)        | (c & 3);           // [0,32)

    const int n = (int)min(fcur[fid], (unsigned)CAP_F);   // n <= 96 = 3*32
    if (n == 0) return;
    const fvec4* seg = fineSeg + (size_t)fid * CAP_F;
    float* lw = &lat[wave][0];

    // ---- wave-level DMA stage: 8 rounds x 64 lanes of 16 B ------------------
    #pragma unroll
    for (int k = 0; k < 8; ++k) {
        const int u  = k * 64 + lane;
        const int uc = min(u, NROWS * 4 - 1);          // clamp tail into pad
        const int r  = uc >> 2, j = uc & 3;
        const int qs = j ^ (r & 3);                    // source-side XOR swizzle
        const int dx = r / 25, rem = r - dx * 25, dy = rem / 5, dz = rem - dy * 5;
        const int gx = min(bx * 4 + dx, 127);
        const int gy = min(by * 4 + dy, 127);
        const int gz = min(bz * 4 + dz, 127);
        const float* src = latents
            + ((size_t)(((gx << 7) | gy) << 7 | gz)) * LATENT_DIM + qs * 4;
        float* dst = lw + k * 256;                     // wave-uniform base; HW adds lane*16B
        __builtin_amdgcn_global_load_lds((gptr_t)(const void*)src,
                                         (lptr_t)(void*)dst, 16, 0, 0);
    }

    // ---- prefetch all tuples (clamped addresses, always issued) -------------
    const int hi = n - 1;
    fvec4 tp[3];
    #pragma unroll
    for (int k = 0; k < 3; ++k)
        tp[k] = __builtin_nontemporal_load(&seg[min(k * 32 + g, hi)]);

    // ---- single wave-level wait; no barriers --------------------------------
    asm volatile("s_waitcnt vmcnt(0)" ::: "memory");
    __builtin_amdgcn_sched_barrier(0);

    // ---- compute: 2 quarters per lane ---------------------------------------
    #pragma unroll
    for (int k = 0; k < 3; ++k) {
        if (k * 32 + g < n) {
            const fvec4 tpv = tp[k];
            const unsigned u  = __float_as_uint(tpv.w);
            const unsigned idx = u & 0x1FFFFFu;
            const int lxl = (u >> 21) & 3, lyl = (u >> 23) & 3, lzl = (u >> 25) & 3;
            const int rr0 = lxl * 25 + lyl * 5 + lzl;

            const float wbx = tpv.x, wby = tpv.y, wbz = tpv.z;
            const float wax = 1.0f - wbx, way = 1.0f - wby, waz = 1.0f - wbz;
            const float fxy[4] = {wax * way, wax * wby, wbx * way, wbx * wby};
            const float fz[2]  = {waz, wbz};

            fvec4 acc0 = (fvec4)(0.0f), acc1 = (fvec4)(0.0f);
            #pragma unroll
            for (int cc = 0; cc < 8; ++cc) {           // _OFFSETS order (x-major)
                const int ox = cc >> 2, oy = (cc >> 1) & 1, oz = cc & 1;
                const int rr = rr0 + ox * 25 + oy * 5 + oz;
                const float w = fxy[ox * 2 + oy] * fz[oz];
                const int fo = rr * 16 + (q0 ^ (rr & 3)) * 4;   // float offset
                const fvec4 f0 = *reinterpret_cast<const fvec4*>(lw + fo);
                const fvec4 f1 = *reinterpret_cast<const fvec4*>(lw + (fo ^ 4));
                acc0 += w * f0;
                acc1 += w * f1;
            }

            float* ob = out + (size_t)idx * LATENT_DIM + q0 * 4;
            __builtin_nontemporal_store(acc0, reinterpret_cast<fvec4*>(ob));
            __builtin_nontemporal_store(acc1, reinterpret_cast<fvec4*>(ob + 4));
        }
    }
}

// ---- spill cleanup (normally tiny; raw tuples) -------------------------------

__global__ __launch_bounds__(256) void spillK(
    const fvec4* __restrict__ spillSeg, const unsigned* __restrict__ spillcur,
    const float* __restrict__ latents, float* __restrict__ out)
{
    const unsigned n = min(*spillcur, (unsigned)SPILL_CAP);
    for (unsigned i = blockIdx.x * 256 + threadIdx.x; i < n; i += gridDim.x * 256) {
        const fvec4 tp = spillSeg[i];
        const unsigned idx = __float_as_uint(tp.w) & 0x1FFFFFu;
        int cx[2], cy[2], cz[2]; float fx[2], fy[2], fz[2];
        corner_setup(tp.x * SCALE, tp.y * SCALE, tp.z * SCALE, cx, cy, cz, fx, fy, fz);
        #pragma unroll
        for (int q = 0; q < 4; ++q) {
            const fvec4 acc = trilerp_q(latents, cx, cy, cz, fx, fy, fz, q);
            *reinterpret_cast<fvec4*>(out + (size_t)idx * LATENT_DIM + q * 4) = acc;
        }
    }
}

// ---- fallback: direct version ----------------------------------------------

__global__ __launch_bounds__(256) void trilerp_direct(
    const float* __restrict__ pts, const float* __restrict__ latents,
    float* __restrict__ out, int n_pts)
{
    const int tid = blockIdx.x * blockDim.x + threadIdx.x;
    const int p = tid >> 2;
    const int q = tid & 3;
    if (p >= n_pts) return;
    int cx[2], cy[2], cz[2]; float fx[2], fy[2], fz[2];
    corner_setup(pts[3*p] * SCALE, pts[3*p+1] * SCALE, pts[3*p+2] * SCALE,
                 cx, cy, cz, fx, fy, fz);
    const fvec4 acc = trilerp_q(latents, cx, cy, cz, fx, fy, fz, q);
    *reinterpret_cast<fvec4*>(out + (size_t)p * LATENT_DIM + q * 4) = acc;
}

// ---- launch -----------------------------------------------------------------

extern "C" void kernel_launch(void* const* d_in, const int* in_sizes, int n_in,
                              void* d_out, int out_size, void* d_ws, size_t ws_size,
                              hipStream_t stream) {
    const float* pts     = (const float*)d_in[0];
    const float* latents = (const float*)d_in[1];
    float* out = (float*)d_out;
    const int n_pts = in_sizes[0] / 3;

    const int cap_s = (int)(((size_t)out_size * 4) / (NSUPER * 16));  // tuples/super seg

    if (ws_size < WS_NEEDED || cap_s * (size_t)NSUPER * 16 > (size_t)out_size * 4 ||
        (size_t)cap_s < (size_t)n_pts / 128 || n_pts > (1 << 21)) {
        const int total = n_pts * 4;
        trilerp_direct<<<(total + 255) / 256, 256, 0, stream>>>(pts, latents, out, n_pts);
        return;
    }

    unsigned* scur     = (unsigned*)((char*)d_ws + SCUR_OFF);
    unsigned* fcur     = (unsigned*)((char*)d_ws + FCUR_OFF);
    unsigned* spillcur = (unsigned*)((char*)d_ws + SPILLCUR_OFF);
    fvec4*    fineSeg  = (fvec4*)((char*)d_ws + FINE_OFF);
    fvec4*    spillSeg = (fvec4*)((char*)d_ws + SPILL_OFF);
    fvec4*    superSeg = (fvec4*)d_out;                 // reused as scratch

    hipMemsetAsync(d_ws, 0, CUR_BYTES, stream);
    binA1<<<256, 256, 0, stream>>>(pts, n_pts, scur, superSeg, cap_s,
                                   spillcur, spillSeg);
    binA2<<<NSUPER * 2, 256, 0, stream>>>(superSeg, cap_s, scur,
                                          fcur, fineSeg, spillcur, spillSeg);
    binB<<<NFINE / 4, 256, 0, stream>>>(fineSeg, fcur, latents, out);
    spillK<<<16, 256, 0, stream>>>(spillSeg, spillcur, latents, out);
}